// Round 1
// baseline (124.886 us; speedup 1.0000x reference)
//
#include <hip/hip_runtime.h>

// N=4, C=32, H=W=256, KS=3, O=C*9=288
// ws layout: p [4,32,32,32] (131072 f). y is no longer materialized.
#define N_ 4
#define C_ 32
#define H_ 256
#define W_ 256
#define O_ 288
#define PH 32
#define P_ELEMS (N_*C_*PH*PH)
#define OUT_ELEMS (N_*C_*H_*W_)

// Kernel 1: psf -> 1/4 bilinear (avg of 2x2 at rows/cols {4o+1,4o+2}) -> maxpool2
__global__ __launch_bounds__(256) void k_downsample(
    const float* __restrict__ psf, float* __restrict__ p) {
  int tid = blockIdx.x * blockDim.x + threadIdx.x;
  if (tid >= P_ELEMS) return;
  int tx = tid & 31;
  int ty = (tid >> 5) & 31;
  int nc = tid >> 10;
  const float* x = psf + (size_t)nc * (H_ * W_);
  float m = -1e30f;
#pragma unroll
  for (int a = 0; a < 2; a++) {
#pragma unroll
    for (int b = 0; b < 2; b++) {
      int r0 = 8 * ty + 4 * a + 1;
      int c0 = 8 * tx + 4 * b;          // 16B-aligned base; cols used: c0+1,c0+2
      const float4 q0 = *(const float4*)(x + r0 * W_ + c0);
      const float4 q1 = *(const float4*)(x + (r0 + 1) * W_ + c0);
      float avg = 0.25f * (q0.y + q0.z + q1.y + q1.z);
      m = fmaxf(m, avg);
    }
  }
  p[tid] = m;
}

// Kernel 2 (fused): per-block 1x1 conv (KPResBlock) for the 9 filter planes
// x 4 y-rows this block's h-band needs, into LDS; then x8 bilinear upsample +
// per-pixel 3x3 dynamic filter, identical structure to the previous k_fac but
// reading tb rows from LDS instead of a materialized global y.
//
// Band math: block covers h in [16a, 16a+16). sh = max(0.125h-0.4375, 0) so
// y0 in {2a-1, 2a, 2a+1}, y1 = y0+1 <= 2a+2 -> rows {2a-1..2a+2} (clamped),
// stored as y_tile logical rows j=0..3, physical row clamp(2a-1+j, 0, 31).
// Conv recompute across overlapping bands is only 2x (rows shared by
// adjacent bands), ~151M lane-FLOPs total ~2us.
__global__ __launch_bounds__(256) void k_fused(
    const float* __restrict__ p, const float* __restrict__ w1,
    const float* __restrict__ b1, const float* __restrict__ ws,
    const float* __restrict__ bs, const float* __restrict__ fm,
    float* __restrict__ out) {
  __shared__ float w1_s[288];
  __shared__ float ws_s[288];
  __shared__ float y_tile[9][4][32];

  int bid = blockIdx.x;                     // 2048 blocks
  int work = (bid >> 3) + (bid & 7) * 256;  // XCD-contiguous plane ranges
  int a = work & 15;                        // 16-row h-band
  int c = (work >> 4) & 31;
  int n = work >> 9;
  int t = threadIdx.x;
  int row_base = 2 * a - 1;

  // ---- stage weights for o in [9c, 9c+9): 288 floats each, coalesced ----
  {
    const float* w1b = w1 + (size_t)c * 9 * 32;
    const float* wsb = ws + (size_t)c * 9 * 32;
    w1_s[t] = w1b[t];
    ws_s[t] = wsb[t];
    if (t < 32) {
      w1_s[256 + t] = w1b[256 + t];
      ws_s[256 + t] = wsb[256 + t];
    }
  }
  __syncthreads();

  // ---- conv phase: y_tile[k][j][col], 9*4*32 = 1152 values ----
  // item = (k, j, col4): one float4 of columns. 288 items; threads cover
  // k=0..7 directly, k=8 by lanes (t&63)<8 of each wave (balanced).
  {
    auto conv_item = [&](int k, int j, int c4) {
      int pr = min(max(row_base + j, 0), 31);
      const float4* pp = (const float4*)p + ((size_t)n * (C_ * 256)) +
                         (pr << 3) + c4;           // + ch*256 per channel
      int o = c * 9 + k;
      float bb1 = b1[o], bbs = bs[o];
      float a1x = bb1, a1y = bb1, a1z = bb1, a1w = bb1;
      float a2x = bbs, a2y = bbs, a2z = bbs, a2w = bbs;
#pragma unroll
      for (int ch = 0; ch < C_; ch++) {
        float4 pv = pp[ch << 8];
        float u1 = w1_s[(k << 5) + ch];
        float u2 = ws_s[(k << 5) + ch];
        a1x = fmaf(pv.x, u1, a1x); a1y = fmaf(pv.y, u1, a1y);
        a1z = fmaf(pv.z, u1, a1z); a1w = fmaf(pv.w, u1, a1w);
        a2x = fmaf(pv.x, u2, a2x); a2y = fmaf(pv.y, u2, a2y);
        a2z = fmaf(pv.z, u2, a2z); a2w = fmaf(pv.w, u2, a2w);
      }
      float4 rr;
      rr.x = ((a1x >= 0.f) ? a1x : 0.2f * a1x) + a2x;
      rr.y = ((a1y >= 0.f) ? a1y : 0.2f * a1y) + a2y;
      rr.z = ((a1z >= 0.f) ? a1z : 0.2f * a1z) + a2z;
      rr.w = ((a1w >= 0.f) ? a1w : 0.2f * a1w) + a2w;
      *(float4*)&y_tile[k][j][c4 << 2] = rr;
    };
    conv_item(t >> 5, (t >> 3) & 3, t & 7);
    if ((t & 63) < 8) conv_item(8, t >> 6, t & 7);
  }
  __syncthreads();

  // ---- fac phase: identical to previous k_fac, tb rows from LDS ----
  int m = t & 31;
  int r = t >> 5;                           // 0..7
  int h0 = (a << 4) + (r << 1);             // even

  float sh0 = fmaxf(0.125f * (float)h0 - 0.4375f, 0.f);
  float sh1 = fmaxf(0.125f * (float)h0 - 0.3125f, 0.f);   // h0+1
  int y0 = (int)sh0;
  float wy0 = sh0 - (float)y0;
  float wy1 = sh1 - (float)y0;              // same y0 (frac never crosses int)
  int y0l = y0 - row_base;                  // logical row in y_tile: 0..2

  float tbA[9], tbB[9];
#pragma unroll
  for (int k = 0; k < 9; k++) {
    float t0 = y_tile[k][y0l][m];
    float u0 = y_tile[k][y0l + 1][m];       // physical clamp handled at stage
    float d = u0 - t0;
    tbA[k] = fmaf(wy0, d, t0);
    tbB[k] = fmaf(wy1, d, t0);
  }
  int cm1 = max(m - 1, 0);
  int cp1 = min(m + 1, 31);

  const float* fb = fm + ((size_t)(n * C_ + c) << 16);

  float acc[16];
#pragma unroll
  for (int j = 0; j < 16; j++) acc[j] = 0.f;

#pragma unroll
  for (int i = 0; i < 4; i++) {             // fm rows h0-1 .. h0+2
    int row = h0 - 1 + i;
    float fv[10];
    if (row >= 0 && row < 256) {            // uniform within 32-lane group
      const float* fr = fb + (row << 8) + (m << 3);
      float4 q0 = *(const float4*)(fr);
      float4 q1 = *(const float4*)(fr + 4);
      float left = __shfl(q1.w, cm1, 32);
      float right = __shfl(q0.x, cp1, 32);
      fv[0] = (m > 0) ? left : 0.f;
      fv[1] = q0.x; fv[2] = q0.y; fv[3] = q0.z; fv[4] = q0.w;
      fv[5] = q1.x; fv[6] = q1.y; fv[7] = q1.z; fv[8] = q1.w;
      fv[9] = (m < 31) ? right : 0.f;
    } else {
#pragma unroll
      for (int tt = 0; tt < 10; tt++) fv[tt] = 0.f;
    }
    // row contributes as ky=i to output h0 (i<=2), ky=i-1 to h0+1 (i>=1)
#pragma unroll
    for (int kx = 0; kx < 3; kx++) {
      if (i <= 2) {
        int k = 3 * i + kx;
        float tbm = tbA[k];
        float tbl = __shfl(tbm, cm1, 32);
        float tbr = __shfl(tbm, cp1, 32);
        float d0 = tbm - tbl;
        float d1 = tbr - tbm;
        acc[0] = fmaf(fv[0 + kx], fmaf(0.5625f, d0, tbl), acc[0]);
        acc[1] = fmaf(fv[1 + kx], fmaf(0.6875f, d0, tbl), acc[1]);
        acc[2] = fmaf(fv[2 + kx], fmaf(0.8125f, d0, tbl), acc[2]);
        acc[3] = fmaf(fv[3 + kx], fmaf(0.9375f, d0, tbl), acc[3]);
        acc[4] = fmaf(fv[4 + kx], fmaf(0.0625f, d1, tbm), acc[4]);
        acc[5] = fmaf(fv[5 + kx], fmaf(0.1875f, d1, tbm), acc[5]);
        acc[6] = fmaf(fv[6 + kx], fmaf(0.3125f, d1, tbm), acc[6]);
        acc[7] = fmaf(fv[7 + kx], fmaf(0.4375f, d1, tbm), acc[7]);
      }
      if (i >= 1) {
        int k = 3 * (i - 1) + kx;
        float tbm = tbB[k];
        float tbl = __shfl(tbm, cm1, 32);
        float tbr = __shfl(tbm, cp1, 32);
        float d0 = tbm - tbl;
        float d1 = tbr - tbm;
        acc[8]  = fmaf(fv[0 + kx], fmaf(0.5625f, d0, tbl), acc[8]);
        acc[9]  = fmaf(fv[1 + kx], fmaf(0.6875f, d0, tbl), acc[9]);
        acc[10] = fmaf(fv[2 + kx], fmaf(0.8125f, d0, tbl), acc[10]);
        acc[11] = fmaf(fv[3 + kx], fmaf(0.9375f, d0, tbl), acc[11]);
        acc[12] = fmaf(fv[4 + kx], fmaf(0.0625f, d1, tbm), acc[12]);
        acc[13] = fmaf(fv[5 + kx], fmaf(0.1875f, d1, tbm), acc[13]);
        acc[14] = fmaf(fv[6 + kx], fmaf(0.3125f, d1, tbm), acc[14]);
        acc[15] = fmaf(fv[7 + kx], fmaf(0.4375f, d1, tbm), acc[15]);
      }
    }
  }
  float* ob = out + ((size_t)(((n * C_ + c) << 8) + h0) << 8) + (m << 3);
  float4 r0 = {acc[0], acc[1], acc[2], acc[3]};
  float4 r1 = {acc[4], acc[5], acc[6], acc[7]};
  float4 r2 = {acc[8], acc[9], acc[10], acc[11]};
  float4 r3 = {acc[12], acc[13], acc[14], acc[15]};
  *(float4*)(ob) = r0;
  *(float4*)(ob + 4) = r1;
  *(float4*)(ob + 256) = r2;               // row h0+1
  *(float4*)(ob + 260) = r3;
}

extern "C" void kernel_launch(void* const* d_in, const int* in_sizes, int n_in,
                              void* d_out, int out_size, void* d_ws,
                              size_t ws_size, hipStream_t stream) {
  const float* psf = (const float*)d_in[0];
  const float* fm = (const float*)d_in[1];
  const float* w1 = (const float*)d_in[2];
  const float* b1 = (const float*)d_in[3];
  const float* ws = (const float*)d_in[4];
  const float* bs = (const float*)d_in[5];
  float* out = (float*)d_out;

  float* p = (float*)d_ws;

  k_downsample<<<P_ELEMS / 256, 256, 0, stream>>>(psf, p);
  k_fused<<<OUT_ELEMS / (16 * 256), 256, 0, stream>>>(p, w1, b1, ws, bs, fm, out);
}